// Round 1
// baseline (2303.708 us; speedup 1.0000x reference)
//
#include <hip/hip_runtime.h>
#include <math.h>

constexpr int N = 128;
constexpr int V = 50257;
constexpr int H = 4096;
constexpr int L = 200;

constexpr int BN = 64;          // vocab tile per workgroup
constexpr int BK = 32;          // k tile
constexpr int NB = 2048;        // histogram bins per level
constexpr int XCAP = 1024;      // exact-candidate list capacity
constexpr int VMAIN = (V / 1024) * 1024;  // 50176, 4-way-unrolled main span

struct RowStats {
  float m, inv_w1, hi2, inv_w2, tstar, Z;
  int bstar, fstar, istar, pad;
};

// ---------------- GEMM: logits[n][v] = dot(hs[n,:], emb[v,:]) / T[n] ----------------
// fp32 SIMT, BM=128 (all rows) x BN=64 tile; LDS-staged with XOR swizzle on the
// float4 column keyed by (row>>3)&7 -> conflict-free fragment reads.
__global__ __launch_bounds__(256)
void sampler_gemm(const float* __restrict__ A, const float* __restrict__ B,
                  const float* __restrict__ temps, float* __restrict__ out)
{
  __shared__ float As[128][36];
  __shared__ float Bs[BN][36];
  const int tid = threadIdx.x;
  const int v0 = blockIdx.x * BN;
  const int tx = tid & 15;   // 16 vocab groups of 4
  const int ty = tid >> 4;   // 16 row groups of 8

  float acc[8][4];
#pragma unroll
  for (int i = 0; i < 8; i++)
#pragma unroll
    for (int j = 0; j < 4; j++) acc[i][j] = 0.f;

  for (int k0 = 0; k0 < H; k0 += BK) {
#pragma unroll
    for (int t = 0; t < 4; t++) {           // A tile: 128x32 = 1024 float4
      int i = tid + 256 * t;
      int r = i >> 3, c4 = i & 7;
      float4 val = *(const float4*)(A + (size_t)r * H + k0 + c4 * 4);
      *(float4*)&As[r][((c4 ^ ((r >> 3) & 7)) << 2)] = val;
    }
#pragma unroll
    for (int t = 0; t < 2; t++) {           // B tile: 64x32 = 512 float4
      int i = tid + 256 * t;
      int r = i >> 3, c4 = i & 7;
      int v = v0 + r; if (v >= V) v = V - 1;
      float4 val = *(const float4*)(B + (size_t)v * H + k0 + c4 * 4);
      *(float4*)&Bs[r][((c4 ^ ((r >> 3) & 7)) << 2)] = val;
    }
    __syncthreads();
#pragma unroll
    for (int c4 = 0; c4 < 8; c4++) {
      float4 a4[8], b4[4];
#pragma unroll
      for (int i = 0; i < 8; i++) {
        int r = ty * 8 + i;
        a4[i] = *(const float4*)&As[r][((c4 ^ ((r >> 3) & 7)) << 2)];
      }
#pragma unroll
      for (int j = 0; j < 4; j++) {
        int r = tx * 4 + j;
        b4[j] = *(const float4*)&Bs[r][((c4 ^ ((r >> 3) & 7)) << 2)];
      }
#pragma unroll
      for (int i = 0; i < 8; i++)
#pragma unroll
        for (int j = 0; j < 4; j++) {
          acc[i][j] += a4[i].x * b4[j].x;
          acc[i][j] += a4[i].y * b4[j].y;
          acc[i][j] += a4[i].z * b4[j].z;
          acc[i][j] += a4[i].w * b4[j].w;
        }
    }
    __syncthreads();
  }

#pragma unroll
  for (int i = 0; i < 8; i++) {
    int r = ty * 8 + i;
    float T = temps[r];
#pragma unroll
    for (int j = 0; j < 4; j++) {
      int v = v0 + tx * 4 + j;
      if (v < V) out[(size_t)r * V + v] = acc[i][j] / T;
    }
  }
}

// ---------------- penalties fixup (<=200 tokens/row; first-occurrence = unique writer) ----
// logits already temp-scaled: (x/rp)/T == (x/T)/rp, and freq/pres get folded by /T.
__global__ __launch_bounds__(256)
void sampler_fixup(float* __restrict__ logits, const int* __restrict__ toks,
                   const float* __restrict__ pres, const float* __restrict__ freq,
                   const float* __restrict__ rep, const float* __restrict__ temps)
{
  int n = blockIdx.x, l = threadIdx.x;
  if (l >= L) return;
  const int* row = toks + n * L;
  int tok = row[l];
  for (int j = 0; j < l; j++)
    if (row[j] == tok) return;                // not first occurrence
  int c = 0;
  for (int j = 0; j < L; j++) c += (row[j] == tok) ? 1 : 0;
  float T = temps[n];
  float x = logits[(size_t)n * V + tok];
  float rp = rep[n];
  x = (x > 0.f) ? (x / rp) : (x * rp);        // sign(x/T)==sign(x)
  x -= (freq[n] * (float)c + pres[n]) / T;
  logits[(size_t)n * V + tok] = x;
}

// ---------------- per-row selection: 2-level histogram radix-select + exact tie walk ----
__global__ __launch_bounds__(256)
void sampler_select(const float* __restrict__ logits,
                    const float* __restrict__ top_ps, const int* __restrict__ top_ks,
                    RowStats* __restrict__ stats)
{
  const int n = blockIdx.x;
  const int tid = threadIdx.x;
  const float* __restrict__ xr = logits + (size_t)n * V;

  __shared__ float s_esum[NB];
  __shared__ unsigned s_cnt[NB];
  __shared__ float s_red[256];
  __shared__ float s_xl[XCAP];
  __shared__ int s_il[XCAP];
  __shared__ unsigned s_num;
  __shared__ int s_i[2];

  const float P = top_ps[n];
  const int K = top_ks[n];

  // ---- pass 0: row max / min (4-way unrolled for load ILP) ----
  float lmax = -3.402823466e38f, lmin = 3.402823466e38f;
  for (int v = tid; v < VMAIN; v += 1024) {
    float t0 = xr[v], t1 = xr[v + 256], t2 = xr[v + 512], t3 = xr[v + 768];
    lmax = fmaxf(lmax, fmaxf(fmaxf(t0, t1), fmaxf(t2, t3)));
    lmin = fminf(lmin, fminf(fminf(t0, t1), fminf(t2, t3)));
  }
  for (int v = VMAIN + tid; v < V; v += 256) {
    float t = xr[v];
    lmax = fmaxf(lmax, t); lmin = fminf(lmin, t);
  }
  s_red[tid] = lmax; __syncthreads();
  for (int s = 128; s > 0; s >>= 1) {
    if (tid < s) s_red[tid] = fmaxf(s_red[tid], s_red[tid + s]);
    __syncthreads();
  }
  const float m = s_red[0];
  __syncthreads();
  s_red[tid] = lmin; __syncthreads();
  for (int s = 128; s > 0; s >>= 1) {
    if (tid < s) s_red[tid] = fminf(s_red[tid], s_red[tid + s]);
    __syncthreads();
  }
  const float rmin = s_red[0];
  __syncthreads();

  const float range = fmaxf(m - rmin, 1e-20f);
  const float inv_w1 = ((float)NB / range) * (1.f - 1e-6f);
  const float w1 = 1.f / inv_w1;

  for (int i = tid; i < NB; i += 256) { s_cnt[i] = 0u; s_esum[i] = 0.f; }
  __syncthreads();

  // ---- pass 1: level-1 histogram (count + expsum) and S_all ----
  float lsum = 0.f;
  {
    auto proc = [&](float t) {
      float e = __expf(t - m);
      lsum += e;
      int b = (int)((m - t) * inv_w1);
      b = b > NB - 1 ? NB - 1 : b;
      atomicAdd(&s_esum[b], e);
      atomicAdd(&s_cnt[b], 1u);
    };
    for (int v = tid; v < VMAIN; v += 1024) {
      float t0 = xr[v], t1 = xr[v + 256], t2 = xr[v + 512], t3 = xr[v + 768];
      proc(t0); proc(t1); proc(t2); proc(t3);
    }
    for (int v = VMAIN + tid; v < V; v += 256) proc(xr[v]);
  }
  __syncthreads();
  s_red[tid] = lsum; __syncthreads();
  for (int s = 128; s > 0; s >>= 1) {
    if (tid < s) s_red[tid] += s_red[tid + s];
    __syncthreads();
  }
  const float S_all = s_red[0];
  const float thresh = P * S_all;
  __syncthreads();

  // ---- scan level-1 bins: first bin whose full inclusion violates top-k or top-p ----
  int accA = 0; float accE = 0.f;   // only thread 0's copy is meaningful
  if (tid == 0) {
    int bs = NB - 1;
    for (int b = 0; b < NB; b++) {
      unsigned c = s_cnt[b];
      float e = s_esum[b];
      if ((accA + (int)c > K) || (accE + e > thresh)) { bs = b; break; }
      accA += (int)c; accE += e;
    }
    s_i[0] = bs;
    s_num = 0u;
  }
  __syncthreads();
  const int bstar = s_i[0];
  const float hi2 = m - (float)bstar * w1;     // identical on all threads; stored for reuse
  const float inv_w2 = inv_w1 * (float)NB;

  for (int i = tid; i < NB; i += 256) { s_cnt[i] = 0u; s_esum[i] = 0.f; }
  __syncthreads();

  // ---- pass 2: level-2 histogram inside bin bstar ----
  {
    auto proc = [&](float t) {
      int b = (int)((m - t) * inv_w1);
      b = b > NB - 1 ? NB - 1 : b;
      if (b == bstar) {
        int b2 = (int)((hi2 - t) * inv_w2);
        b2 = b2 < 0 ? 0 : (b2 > NB - 1 ? NB - 1 : b2);
        atomicAdd(&s_esum[b2], __expf(t - m));
        atomicAdd(&s_cnt[b2], 1u);
      }
    };
    for (int v = tid; v < VMAIN; v += 1024) {
      float t0 = xr[v], t1 = xr[v + 256], t2 = xr[v + 512], t3 = xr[v + 768];
      proc(t0); proc(t1); proc(t2); proc(t3);
    }
    for (int v = VMAIN + tid; v < V; v += 256) proc(xr[v]);
  }
  __syncthreads();

  if (tid == 0) {
    int fs = NB - 1;   // fallback (fp jitter): exact walk then covers last fine bin
    for (int b = 0; b < NB; b++) {
      unsigned c = s_cnt[b];
      float e = s_esum[b];
      if ((accA + (int)c > K) || (accE + e > thresh)) { fs = b; break; }
      accA += (int)c; accE += e;
    }
    s_i[1] = fs;
  }
  __syncthreads();
  const int fstar = s_i[1];

  // ---- gather exact candidates in the boundary fine bin ----
  {
    auto proc = [&](float t, int v) {
      int b = (int)((m - t) * inv_w1);
      b = b > NB - 1 ? NB - 1 : b;
      if (b == bstar) {
        int b2 = (int)((hi2 - t) * inv_w2);
        b2 = b2 < 0 ? 0 : (b2 > NB - 1 ? NB - 1 : b2);
        if (b2 == fstar) {
          unsigned p = atomicAdd(&s_num, 1u);
          if (p < XCAP) { s_xl[p] = t; s_il[p] = v; }
        }
      }
    };
    for (int v = tid; v < VMAIN; v += 1024) {
      proc(xr[v], v); proc(xr[v + 256], v + 256);
      proc(xr[v + 512], v + 512); proc(xr[v + 768], v + 768);
    }
    for (int v = VMAIN + tid; v < V; v += 256) proc(xr[v], v);
  }
  __syncthreads();
  for (int i = tid; i < XCAP; i += 256) s_cnt[i] = 0u;  // reuse as "used" flags
  __syncthreads();

  // ---- exact walk: descending (value, index asc) until a constraint trips ----
  if (tid == 0) {
    unsigned nm = s_num;
    int M = (int)(nm < (unsigned)XCAP ? nm : (unsigned)XCAP);
    float tstar = 3.402823466e38f;  // sentinel: nothing kept in fine bin
    int istar = -1;
    for (int step = 0; step < M; step++) {
      float best = -3.402823466e38f; int bi = -1, bidx = 0x7fffffff;
      for (int i = 0; i < M; i++) {
        if (s_cnt[i]) continue;
        float xv = s_xl[i]; int iv = s_il[i];
        if (xv > best || (xv == best && iv < bidx)) { best = xv; bidx = iv; bi = i; }
      }
      if (bi < 0) break;
      if (accA < K && accE <= thresh) {  // exclusive rank / exclusive cumsum tests
        accA += 1; accE += __expf(best - m);
        tstar = best; istar = bidx;
        s_cnt[bi] = 1u;
      } else break;
    }
    RowStats st;
    st.m = m; st.inv_w1 = inv_w1; st.hi2 = hi2; st.inv_w2 = inv_w2;
    st.tstar = tstar; st.Z = accE;     // Z = sum of exp over kept set
    st.bstar = bstar; st.fstar = fstar; st.istar = istar; st.pad = 0;
    stats[n] = st;
  }
}

// ---------------- final: in-place masked softmax over d_out ----------------
__global__ __launch_bounds__(256)
void sampler_final(float* __restrict__ buf, const RowStats* __restrict__ stats)
{
  const int n = blockIdx.y;
  const int v = blockIdx.x * 256 + threadIdx.x;
  if (v >= V) return;
  const RowStats* st = stats + n;
  const float m = st->m, inv_w1 = st->inv_w1, hi2 = st->hi2, inv_w2 = st->inv_w2;
  const float tstar = st->tstar, Z = st->Z;
  const int bstar = st->bstar, fstar = st->fstar, istar = st->istar;

  float x = buf[(size_t)n * V + v];
  int b = (int)((m - x) * inv_w1);        // identical arithmetic to select kernel
  b = b > NB - 1 ? NB - 1 : b;
  bool kept;
  if (b < bstar) kept = true;
  else if (b > bstar) kept = false;
  else {
    int b2 = (int)((hi2 - x) * inv_w2);
    b2 = b2 < 0 ? 0 : (b2 > NB - 1 ? NB - 1 : b2);
    if (b2 < fstar) kept = true;
    else if (b2 > fstar) kept = false;
    else kept = (x > tstar) || (x == tstar && v <= istar);
  }
  buf[(size_t)n * V + v] = kept ? (__expf(x - m) / Z) : 0.f;
}

extern "C" void kernel_launch(void* const* d_in, const int* in_sizes, int n_in,
                              void* d_out, int out_size, void* d_ws, size_t ws_size,
                              hipStream_t stream) {
  const float* hs    = (const float*)d_in[0];
  const float* emb   = (const float*)d_in[1];
  const int*   toks  = (const int*)d_in[2];
  const float* pres  = (const float*)d_in[3];
  const float* freq  = (const float*)d_in[4];
  const float* rep   = (const float*)d_in[5];
  const float* temps = (const float*)d_in[6];
  const float* tps   = (const float*)d_in[7];
  const int*   tks   = (const int*)d_in[8];
  float* out = (float*)d_out;           // logits live here, transformed in place
  RowStats* stats = (RowStats*)d_ws;    // ~5 KB

  sampler_gemm <<<dim3((V + BN - 1) / BN), dim3(256), 0, stream>>>(hs, emb, temps, out);
  sampler_fixup<<<dim3(N),                 dim3(256), 0, stream>>>(out, toks, pres, freq, rep, temps);
  sampler_select<<<dim3(N),                dim3(256), 0, stream>>>(out, tps, tks, stats);
  sampler_final<<<dim3((V + 255) / 256, N), dim3(256), 0, stream>>>(out, stats);
}

// Round 2
// 2217.987 us; speedup vs baseline: 1.0386x; 1.0386x over previous
//
#include <hip/hip_runtime.h>
#include <math.h>
#include <float.h>

constexpr int N = 128;
constexpr int V = 50257;
constexpr int H = 4096;
constexpr int L = 200;

constexpr int NB = 4096;            // histogram bins (fixed range)
constexpr float RANGE = 48.0f;      // covers max span of (rowmax - logit)
constexpr int XCAP = 2048;          // boundary-bin candidate capacity

using short8 = __attribute__((ext_vector_type(8))) short;  // 8 bf16
using f32x4  = __attribute__((ext_vector_type(4))) float;

struct RowStats { float m, tstar, Z; int bstar, istar; int pad[3]; };  // 32 B

// shared by select & final: MUST be bit-identical in both
__device__ __forceinline__ int bin_of(float m, float x) {
  float d = (m - x) * ((float)NB / RANGE);
  int b = (int)d;
  return b < 0 ? 0 : (b > NB - 1 ? NB - 1 : b);
}

// ---------------- prep: split A (fp32) into bf16 hi/lo (truncation) ----------------
__global__ __launch_bounds__(256)
void sampler_prep(const float* __restrict__ A, ushort* __restrict__ Ahi,
                  ushort* __restrict__ Alo)
{
  int i = (blockIdx.x * 256 + threadIdx.x) * 4;
  float4 f = *(const float4*)(A + i);
  float x[4] = {f.x, f.y, f.z, f.w};
  ushort h[4], l[4];
#pragma unroll
  for (int j = 0; j < 4; j++) {
    uint b = __float_as_uint(x[j]);
    h[j] = (ushort)(b >> 16);
    float hif = __uint_as_float(b & 0xFFFF0000u);
    l[j] = (ushort)(__float_as_uint(x[j] - hif) >> 16);   // x - hif exact in fp32
  }
  *(ushort4*)(Ahi + i) = make_ushort4(h[0], h[1], h[2], h[3]);
  *(ushort4*)(Alo + i) = make_ushort4(l[0], l[1], l[2], l[3]);
}

// ---------------- GEMM: C[r][v] = dot(A[r,:], B[v,:]) / T[r] ----------------
// Split-bf16 MFMA (hi/lo), NT layout, no LDS. Block = 4 waves, tile 128(M) x 64(N);
// wave w covers cols v0+w*16..+15; per wave 8 m-tiles of 16x16x32, 3 MFMA each.
// B (823 MB) converted in-register; A-frags read from pre-split global (L2-resident).
__global__ __launch_bounds__(256)
void sampler_gemm(const ushort* __restrict__ Ahi, const ushort* __restrict__ Alo,
                  const float* __restrict__ B, const float* __restrict__ temps,
                  float* __restrict__ out)
{
  const int tid = threadIdx.x;
  const int wave = tid >> 6;
  const int lane = tid & 63;
  const int c = lane & 15;        // A m-index, B n-index, D col
  const int quad = lane >> 4;     // k-group (k = quad*8 + j)
  const int v = blockIdx.x * 64 + wave * 16 + c;
  const int vc = v < V ? v : V - 1;

  const float*  Bp  = B   + (size_t)vc * H + quad * 8;
  const ushort* Ahp = Ahi + (size_t)c  * H + quad * 8;
  const ushort* Alp = Alo + (size_t)c  * H + quad * 8;

  f32x4 acc[8];
#pragma unroll
  for (int mt = 0; mt < 8; mt++) acc[mt] = (f32x4){0.f, 0.f, 0.f, 0.f};

  for (int k0 = 0; k0 < H; k0 += 32) {
    float4 b0 = *(const float4*)(Bp + k0);
    float4 b1 = *(const float4*)(Bp + k0 + 4);
    short8 bh, bl;
    {
      float xx[8] = {b0.x, b0.y, b0.z, b0.w, b1.x, b1.y, b1.z, b1.w};
#pragma unroll
      for (int j = 0; j < 8; j++) {
        uint bb = __float_as_uint(xx[j]);
        bh[j] = (short)(bb >> 16);
        float hif = __uint_as_float(bb & 0xFFFF0000u);
        bl[j] = (short)(__float_as_uint(xx[j] - hif) >> 16);
      }
    }
    short8 ah[8], al[8];
#pragma unroll
    for (int mt = 0; mt < 8; mt++) {
      size_t off = (size_t)mt * 16 * H + k0;
      ah[mt] = *(const short8*)(Ahp + off);
      al[mt] = *(const short8*)(Alp + off);
    }
#pragma unroll
    for (int mt = 0; mt < 8; mt++) {   // (Ah+Al)(Bh+Bl) ~ AhBh + AhBl + AlBh
      acc[mt] = __builtin_amdgcn_mfma_f32_16x16x32_bf16(ah[mt], bh, acc[mt], 0, 0, 0);
      acc[mt] = __builtin_amdgcn_mfma_f32_16x16x32_bf16(ah[mt], bl, acc[mt], 0, 0, 0);
      acc[mt] = __builtin_amdgcn_mfma_f32_16x16x32_bf16(al[mt], bh, acc[mt], 0, 0, 0);
    }
  }

  if (v < V) {
#pragma unroll
    for (int mt = 0; mt < 8; mt++)
#pragma unroll
      for (int r4 = 0; r4 < 4; r4++) {          // C/D: col=lane&15, row=quad*4+reg
        int r = mt * 16 + quad * 4 + r4;
        out[(size_t)r * V + v] = acc[mt][r4] / temps[r];
      }
  }
}

// ---------------- penalties fixup (first-occurrence thread = unique writer) ----------
__global__ __launch_bounds__(256)
void sampler_fixup(float* __restrict__ logits, const int* __restrict__ toks,
                   const float* __restrict__ pres, const float* __restrict__ freq,
                   const float* __restrict__ rep, const float* __restrict__ temps)
{
  int n = blockIdx.x, l = threadIdx.x;
  if (l >= L) return;
  const int* row = toks + n * L;
  int tok = row[l];
  for (int j = 0; j < l; j++)
    if (row[j] == tok) return;
  int cnum = 0;
  for (int j = 0; j < L; j++) cnum += (row[j] == tok) ? 1 : 0;
  float T = temps[n];
  float x = logits[(size_t)n * V + tok];
  float rp = rep[n];
  x = (x > 0.f) ? (x / rp) : (x * rp);
  x -= (freq[n] * (float)cnum + pres[n]) / T;
  logits[(size_t)n * V + tok] = x;
}

// ---------------- row max (after fixup) ----------------
__global__ __launch_bounds__(256)
void sampler_rowmax(const float* __restrict__ buf, RowStats* __restrict__ stats)
{
  int n = blockIdx.x, tid = threadIdx.x;
  const float* xr = buf + (size_t)n * V;
  __shared__ float s_red[256];
  float mx = -FLT_MAX;
  for (int v = tid; v < V; v += 256) mx = fmaxf(mx, xr[v]);
  s_red[tid] = mx; __syncthreads();
  for (int s = 128; s > 0; s >>= 1) {
    if (tid < s) s_red[tid] = fmaxf(s_red[tid], s_red[tid + s]);
    __syncthreads();
  }
  if (tid == 0) stats[n].m = s_red[0];
}

// ---------------- select: 1-level hist + parallel scan + boundary-bin exact walk ------
__global__ __launch_bounds__(256)
void sampler_select(const float* __restrict__ logits, const float* __restrict__ top_ps,
                    const int* __restrict__ top_ks, RowStats* __restrict__ stats)
{
  const int n = blockIdx.x, tid = threadIdx.x;
  const float* __restrict__ xr = logits + (size_t)n * V;

  __shared__ unsigned s_cnt[NB];
  __shared__ float s_esum[NB];
  __shared__ unsigned s_pc[256];
  __shared__ float s_pe[256];
  __shared__ float s_xl[XCAP];
  __shared__ int s_il[XCAP];
  __shared__ int s_bstar;
  __shared__ int s_accA;
  __shared__ float s_accE;
  __shared__ unsigned s_num;

  const float m = stats[n].m;
  const float P = top_ps[n];
  const int K = top_ks[n];

  for (int i = tid; i < NB; i += 256) { s_cnt[i] = 0u; s_esum[i] = 0.f; }
  if (tid == 0) { s_bstar = NB; s_num = 0u; }
  __syncthreads();

  // pass 1: histogram (count + expsum)
  for (int v = tid; v < V; v += 256) {
    float t = xr[v];
    int b = bin_of(m, t);
    atomicAdd(&s_esum[b], __expf(t - m));
    atomicAdd(&s_cnt[b], 1u);
  }
  __syncthreads();

  // inclusive prefix over NB bins: 16 bins/thread + 256-wide scan
  const int base = tid * (NB / 256);
  unsigned pc = 0; float pe = 0.f;
  for (int j = 0; j < NB / 256; j++) { pc += s_cnt[base + j]; pe += s_esum[base + j]; }
  s_pc[tid] = pc; s_pe[tid] = pe;
  __syncthreads();
  for (int off = 1; off < 256; off <<= 1) {
    unsigned cp = 0; float ep = 0.f;
    if (tid >= off) { cp = s_pc[tid - off]; ep = s_pe[tid - off]; }
    __syncthreads();
    s_pc[tid] += cp; s_pe[tid] += ep;
    __syncthreads();
  }
  const float S_all = s_pe[255];
  const float thresh = P * S_all;

  // boundary bin: first b with C_incl(b) > K or E_incl(b) > thresh (monotone)
  {
    int ca = (int)(tid ? s_pc[tid - 1] : 0u);
    float ea = tid ? s_pe[tid - 1] : 0.f;
    int found = NB;
    for (int j = 0; j < NB / 256; j++) {
      int cb = (int)s_cnt[base + j]; float eb = s_esum[base + j];
      if ((ca + cb > K) || (ea + eb > thresh)) { found = base + j; break; }
      ca += cb; ea += eb;
    }
    if (found < NB) atomicMin(&s_bstar, found);
  }
  __syncthreads();
  const int bstar = s_bstar;   // always < NB: C(NB-1)=V > K
  if (tid == (bstar >> 4)) {   // owner recomputes exclusive prefix at bstar
    int ca = (int)(tid ? s_pc[tid - 1] : 0u);
    float ea = tid ? s_pe[tid - 1] : 0.f;
    for (int j = base; j < bstar; j++) { ca += (int)s_cnt[j]; ea += s_esum[j]; }
    s_accA = ca; s_accE = ea;
  }
  __syncthreads();

  // pass 2: gather boundary-bin candidates
  for (int v = tid; v < V; v += 256) {
    float t = xr[v];
    if (bin_of(m, t) == bstar) {
      unsigned p = atomicAdd(&s_num, 1u);
      if (p < (unsigned)XCAP) { s_xl[p] = t; s_il[p] = v; }
    }
  }
  __syncthreads();

  // exact walk in (value desc, index asc) order with exclusive-cumsum tests
  if (tid == 0) {
    int M = (int)(s_num < (unsigned)XCAP ? s_num : (unsigned)XCAP);
    int accA = s_accA; float accE = s_accE;
    float tstar = FLT_MAX; int istar = -1;
    for (;;) {
      float best = -FLT_MAX; int bidx = 0x7fffffff; bool found = false;
      for (int i = 0; i < M; i++) {
        float xv = s_xl[i]; int iv = s_il[i];
        bool after = (xv < tstar) || (xv == tstar && iv > istar);
        if (!after) continue;
        if (!found || xv > best || (xv == best && iv < bidx)) {
          best = xv; bidx = iv; found = true;
        }
      }
      if (!found) break;
      if (accA < K && accE <= thresh) {
        accA++; accE += __expf(best - m);
        tstar = best; istar = bidx;
      } else break;
    }
    RowStats st;
    st.m = m; st.tstar = tstar; st.Z = accE;
    st.bstar = bstar; st.istar = istar;
    st.pad[0] = st.pad[1] = st.pad[2] = 0;
    stats[n] = st;
  }
}

// ---------------- final: in-place masked softmax ----------------
__global__ __launch_bounds__(256)
void sampler_final(float* __restrict__ buf, const RowStats* __restrict__ stats)
{
  int n = blockIdx.y;
  int v = blockIdx.x * 256 + threadIdx.x;
  if (v >= V) return;
  RowStats st = stats[n];
  float x = buf[(size_t)n * V + v];
  int b = bin_of(st.m, x);
  bool kept = (b < st.bstar) ||
              (b == st.bstar && (x > st.tstar || (x == st.tstar && v <= st.istar)));
  buf[(size_t)n * V + v] = kept ? (__expf(x - st.m) / st.Z) : 0.f;
}

extern "C" void kernel_launch(void* const* d_in, const int* in_sizes, int n_in,
                              void* d_out, int out_size, void* d_ws, size_t ws_size,
                              hipStream_t stream) {
  const float* hs    = (const float*)d_in[0];
  const float* emb   = (const float*)d_in[1];
  const int*   toks  = (const int*)d_in[2];
  const float* pres  = (const float*)d_in[3];
  const float* freq  = (const float*)d_in[4];
  const float* rep   = (const float*)d_in[5];
  const float* temps = (const float*)d_in[6];
  const float* tps   = (const float*)d_in[7];
  const int*   tks   = (const int*)d_in[8];
  float* out = (float*)d_out;

  char* ws = (char*)d_ws;
  RowStats* stats = (RowStats*)ws;                       // 4 KB
  ushort* Ahi = (ushort*)(ws + 8192);                    // 1 MB
  ushort* Alo = (ushort*)(ws + 8192 + (size_t)N * H * 2);// 1 MB

  sampler_prep  <<<dim3(N * H / 1024),        dim3(256), 0, stream>>>(hs, Ahi, Alo);
  sampler_gemm  <<<dim3((V + 63) / 64),       dim3(256), 0, stream>>>(Ahi, Alo, emb, temps, out);
  sampler_fixup <<<dim3(N),                   dim3(256), 0, stream>>>(out, toks, pres, freq, rep, temps);
  sampler_rowmax<<<dim3(N),                   dim3(256), 0, stream>>>(out, stats);
  sampler_select<<<dim3(N),                   dim3(256), 0, stream>>>(out, tps, tks, stats);
  sampler_final <<<dim3((V + 255) / 256, N),  dim3(256), 0, stream>>>(out, stats);
}

// Round 3
// 2096.713 us; speedup vs baseline: 1.0987x; 1.0578x over previous
//
#include <hip/hip_runtime.h>
#include <math.h>
#include <float.h>

constexpr int N = 128;
constexpr int V = 50257;
constexpr int H = 4096;
constexpr int L = 200;

constexpr int NB1 = 1024;             // coarse bins
constexpr int NB2 = 1024;             // fine bins (within boundary coarse bin)
constexpr float RANGE = 48.0f;        // covers (rowmax - logit) span with margin
constexpr float W1 = RANGE / (float)NB1;          // 0.046875 (exact)
constexpr float INV_W1 = (float)NB1 / RANGE;
constexpr float INV_W2 = (float)NB1 * (float)NB2 / RANGE;
constexpr int XCAP = 2048;            // coarse boundary-bin candidate capacity
constexpr int XCAP2 = 256;            // fine boundary-bin candidate capacity

using short8 = __attribute__((ext_vector_type(8))) short;  // 8 bf16
using f32x4  = __attribute__((ext_vector_type(4))) float;

struct RowStats { float m, tstar, Z; int bstar, fstar, istar; int pad[2]; };  // 32 B

// binning helpers -- MUST be bit-identical between select & final
__device__ __forceinline__ int bin1_of(float m, float x) {
  int b = (int)((m - x) * INV_W1);
  return b < 0 ? 0 : (b > NB1 - 1 ? NB1 - 1 : b);
}
__device__ __forceinline__ float hi2_of(float m, int bstar) {
  return __fmaf_rn((float)bstar, -W1, m);     // forced fma: identical in both kernels
}
__device__ __forceinline__ int bin2_of(float hi2, float x) {
  int b = (int)((hi2 - x) * INV_W2);
  return b < 0 ? 0 : (b > NB2 - 1 ? NB2 - 1 : b);
}

// ---------------- prep: split A (fp32) into bf16 hi/lo (truncation) ----------------
__global__ __launch_bounds__(256)
void sampler_prep(const float* __restrict__ A, ushort* __restrict__ Ahi,
                  ushort* __restrict__ Alo)
{
  int i = (blockIdx.x * 256 + threadIdx.x) * 4;
  float4 f = *(const float4*)(A + i);
  float x[4] = {f.x, f.y, f.z, f.w};
  ushort h[4], l[4];
#pragma unroll
  for (int j = 0; j < 4; j++) {
    uint b = __float_as_uint(x[j]);
    h[j] = (ushort)(b >> 16);
    float hif = __uint_as_float(b & 0xFFFF0000u);
    l[j] = (ushort)(__float_as_uint(x[j] - hif) >> 16);   // x - hif exact in fp32
  }
  *(ushort4*)(Ahi + i) = make_ushort4(h[0], h[1], h[2], h[3]);
  *(ushort4*)(Alo + i) = make_ushort4(l[0], l[1], l[2], l[3]);
}

// ---------------- GEMM machinery ----------------
__device__ __forceinline__ void split8(const float4& f0, const float4& f1,
                                       short8& hi, short8& lo) {
  float xx[8] = {f0.x, f0.y, f0.z, f0.w, f1.x, f1.y, f1.z, f1.w};
#pragma unroll
  for (int j = 0; j < 8; j++) {
    uint bb = __float_as_uint(xx[j]);
    hi[j] = (short)(bb >> 16);
    float hif = __uint_as_float(bb & 0xFFFF0000u);
    lo[j] = (short)(__float_as_uint(xx[j] - hif) >> 16);
  }
}

struct KBuf { float4 b0, b1; short8 ah[8], al[8]; };

__device__ __forceinline__ void load_kbuf(KBuf& kb, const float* __restrict__ Bp,
                                          const ushort* __restrict__ Ahp,
                                          const ushort* __restrict__ Alp, int k0) {
  kb.b0 = *(const float4*)(Bp + k0);
  kb.b1 = *(const float4*)(Bp + k0 + 4);
#pragma unroll
  for (int mt = 0; mt < 8; mt++) {
    size_t off = (size_t)(mt * 16) * H + k0;
    kb.ah[mt] = *(const short8*)(Ahp + off);
    kb.al[mt] = *(const short8*)(Alp + off);
  }
}

__device__ __forceinline__ void mfma_kbuf(const KBuf& kb, f32x4* acc) {
  short8 bh, bl;
  split8(kb.b0, kb.b1, bh, bl);
#pragma unroll
  for (int mt = 0; mt < 8; mt++) {   // (Ah+Al)(Bh+Bl) ~ AhBh + AhBl + AlBh
    acc[mt] = __builtin_amdgcn_mfma_f32_16x16x32_bf16(kb.ah[mt], bh, acc[mt], 0, 0, 0);
    acc[mt] = __builtin_amdgcn_mfma_f32_16x16x32_bf16(kb.ah[mt], bl, acc[mt], 0, 0, 0);
    acc[mt] = __builtin_amdgcn_mfma_f32_16x16x32_bf16(kb.al[mt], bh, acc[mt], 0, 0, 0);
  }
}

// C[r][v] = dot(A[r,:], B[v,:]) / T[r].  Split-bf16 MFMA, NT, no LDS.
// Block = 4 waves x 16 cols; wave covers 8 m-tiles (all 128 rows).
// Register double-buffered k-loop: prefetch k+32 while MFMAing k.
__global__ __launch_bounds__(256, 2)
void sampler_gemm(const ushort* __restrict__ Ahi, const ushort* __restrict__ Alo,
                  const float* __restrict__ B, const float* __restrict__ temps,
                  float* __restrict__ out)
{
  const int tid = threadIdx.x;
  const int wave = tid >> 6;
  const int lane = tid & 63;
  const int c = lane & 15;        // A m-index, B n-index, D col
  const int quad = lane >> 4;     // k-group (k = quad*8 + j)
  const int v = blockIdx.x * 64 + wave * 16 + c;
  const int vc = v < V ? v : V - 1;

  const float*  Bp  = B   + (size_t)vc * H + quad * 8;
  const ushort* Ahp = Ahi + (size_t)c  * H + quad * 8;
  const ushort* Alp = Alo + (size_t)c  * H + quad * 8;

  f32x4 acc[8];
#pragma unroll
  for (int mt = 0; mt < 8; mt++) acc[mt] = (f32x4){0.f, 0.f, 0.f, 0.f};

  KBuf kb0, kb1;
  load_kbuf(kb0, Bp, Ahp, Alp, 0);
#pragma unroll 1
  for (int k0 = 0; k0 < H - 64; k0 += 64) {
    load_kbuf(kb1, Bp, Ahp, Alp, k0 + 32);
    mfma_kbuf(kb0, acc);
    load_kbuf(kb0, Bp, Ahp, Alp, k0 + 64);
    mfma_kbuf(kb1, acc);
  }
  load_kbuf(kb1, Bp, Ahp, Alp, H - 32);
  mfma_kbuf(kb0, acc);
  mfma_kbuf(kb1, acc);

  if (v < V) {
#pragma unroll
    for (int mt = 0; mt < 8; mt++)
#pragma unroll
      for (int r4 = 0; r4 < 4; r4++) {          // C/D: col=lane&15, row=quad*4+reg
        int r = mt * 16 + quad * 4 + r4;
        out[(size_t)r * V + v] = acc[mt][r4] / temps[r];
      }
  }
}

// ---------------- penalties fixup (first-occurrence thread = unique writer) ----------
__global__ __launch_bounds__(256)
void sampler_fixup(float* __restrict__ logits, const int* __restrict__ toks,
                   const float* __restrict__ pres, const float* __restrict__ freq,
                   const float* __restrict__ rep, const float* __restrict__ temps)
{
  int n = blockIdx.x, l = threadIdx.x;
  if (l >= L) return;
  const int* row = toks + n * L;
  int tok = row[l];
  for (int j = 0; j < l; j++)
    if (row[j] == tok) return;
  int cnum = 0;
  for (int j = 0; j < L; j++) cnum += (row[j] == tok) ? 1 : 0;
  float T = temps[n];
  float x = logits[(size_t)n * V + tok];
  float rp = rep[n];
  x = (x > 0.f) ? (x / rp) : (x * rp);
  x -= (freq[n] * (float)cnum + pres[n]) / T;
  logits[(size_t)n * V + tok] = x;
}

// ---------------- select: rowmax + 2-level hist select + exact tie walk -------------
// 512 threads (2 waves/SIMD), 4-way batched global loads for latency hiding.
__global__ __launch_bounds__(512)
void sampler_select(const float* __restrict__ logits, const float* __restrict__ top_ps,
                    const int* __restrict__ top_ks, RowStats* __restrict__ stats)
{
  const int n = blockIdx.x, tid = threadIdx.x;
  const float* __restrict__ xr = logits + (size_t)n * V;
  constexpr int T = 512;
  constexpr int VB = (V / (4 * T)) * (4 * T);   // 49152

  __shared__ unsigned s_cnt[NB1];
  __shared__ float s_esum[NB1];
  __shared__ unsigned s_pc[T];
  __shared__ float s_pe[T];
  __shared__ float s_xl[XCAP];
  __shared__ int s_il[XCAP];
  __shared__ float s_x2[XCAP2];
  __shared__ int s_i2[XCAP2];
  __shared__ int s_bstar, s_fstar;
  __shared__ int s_accA, s_accA2;
  __shared__ float s_accE, s_accE2;
  __shared__ unsigned s_num, s_num2;
  __shared__ float s_m, s_thresh;

  const float P = top_ps[n];
  const int K = top_ks[n];

  // ---- pass 0: row max ----
  float mx = -FLT_MAX;
  for (int v0 = tid; v0 < VB; v0 += 4 * T) {
    float t0 = xr[v0], t1 = xr[v0 + T], t2 = xr[v0 + 2 * T], t3 = xr[v0 + 3 * T];
    mx = fmaxf(mx, fmaxf(fmaxf(t0, t1), fmaxf(t2, t3)));
  }
  for (int v0 = VB + tid; v0 < V; v0 += T) mx = fmaxf(mx, xr[v0]);
  s_pe[tid] = mx; __syncthreads();
  for (int s = T / 2; s > 0; s >>= 1) {
    if (tid < s) s_pe[tid] = fmaxf(s_pe[tid], s_pe[tid + s]);
    __syncthreads();
  }
  if (tid == 0) s_m = s_pe[0];
  __syncthreads();
  const float m = s_m;

  for (int i = tid; i < NB1; i += T) { s_cnt[i] = 0u; s_esum[i] = 0.f; }
  if (tid == 0) { s_bstar = NB1; s_fstar = NB2; s_num = 0u; s_num2 = 0u; }
  __syncthreads();

  // ---- pass 1: coarse histogram (count + expsum) ----
  {
    auto proc = [&](float t) {
      int b = bin1_of(m, t);
      atomicAdd(&s_esum[b], __expf(t - m));
      atomicAdd(&s_cnt[b], 1u);
    };
    for (int v0 = tid; v0 < VB; v0 += 4 * T) {
      float t0 = xr[v0], t1 = xr[v0 + T], t2 = xr[v0 + 2 * T], t3 = xr[v0 + 3 * T];
      proc(t0); proc(t1); proc(t2); proc(t3);
    }
    for (int v0 = VB + tid; v0 < V; v0 += T) proc(xr[v0]);
  }
  __syncthreads();

  // inclusive prefix over NB1 bins: 2 bins/thread + T-wide scan
  {
    const int base = tid * (NB1 / T);
    unsigned pc = 0; float pe = 0.f;
#pragma unroll
    for (int j = 0; j < NB1 / T; j++) { pc += s_cnt[base + j]; pe += s_esum[base + j]; }
    s_pc[tid] = pc; s_pe[tid] = pe;
    __syncthreads();
    for (int off = 1; off < T; off <<= 1) {
      unsigned cp = 0; float ep = 0.f;
      if (tid >= off) { cp = s_pc[tid - off]; ep = s_pe[tid - off]; }
      __syncthreads();
      s_pc[tid] += cp; s_pe[tid] += ep;
      __syncthreads();
    }
    if (tid == 0) s_thresh = P * s_pe[T - 1];
    __syncthreads();
    const float thresh = s_thresh;

    // first bin where inclusive count > K or inclusive expsum > thresh (monotone)
    int ca = (int)(tid ? s_pc[tid - 1] : 0u);
    float ea = tid ? s_pe[tid - 1] : 0.f;
    int found = NB1;
#pragma unroll
    for (int j = 0; j < NB1 / T; j++) {
      int cb = (int)s_cnt[base + j]; float eb = s_esum[base + j];
      if ((ca + cb > K) || (ea + eb > thresh)) { found = base + j; break; }
      ca += cb; ea += eb;
    }
    if (found < NB1) atomicMin(&s_bstar, found);
    __syncthreads();
    const int bstar = s_bstar;      // always < NB1 (count at last bin = V > K)
    if (tid == (bstar / (NB1 / T))) {
      int ca2 = (int)(tid ? s_pc[tid - 1] : 0u);
      float ea2 = tid ? s_pe[tid - 1] : 0.f;
      for (int j = tid * (NB1 / T); j < bstar; j++) { ca2 += (int)s_cnt[j]; ea2 += s_esum[j]; }
      s_accA = ca2; s_accE = ea2;
    }
  }
  __syncthreads();
  const int bstar = s_bstar;
  const float thresh = s_thresh;

  // ---- pass 2: gather coarse boundary-bin candidates ----
  {
    auto proc = [&](float t, int v0) {
      if (bin1_of(m, t) == bstar) {
        unsigned p = atomicAdd(&s_num, 1u);
        if (p < (unsigned)XCAP) { s_xl[p] = t; s_il[p] = v0; }
      }
    };
    for (int v0 = tid; v0 < VB; v0 += 4 * T) {
      proc(xr[v0], v0); proc(xr[v0 + T], v0 + T);
      proc(xr[v0 + 2 * T], v0 + 2 * T); proc(xr[v0 + 3 * T], v0 + 3 * T);
    }
    for (int v0 = VB + tid; v0 < V; v0 += T) proc(xr[v0], v0);
  }
  __syncthreads();
  const int M1 = (int)(s_num < (unsigned)XCAP ? s_num : (unsigned)XCAP);
  const float hi2 = hi2_of(m, bstar);

  // ---- fine histogram over gathered candidates (LDS only) ----
  for (int i = tid; i < NB2; i += T) { s_cnt[i] = 0u; s_esum[i] = 0.f; }
  __syncthreads();
  for (int i = tid; i < M1; i += T) {
    float t = s_xl[i];
    int b2 = bin2_of(hi2, t);
    atomicAdd(&s_esum[b2], __expf(t - m));
    atomicAdd(&s_cnt[b2], 1u);
  }
  __syncthreads();
  {
    const int base = tid * (NB2 / T);
    unsigned pc = 0; float pe = 0.f;
#pragma unroll
    for (int j = 0; j < NB2 / T; j++) { pc += s_cnt[base + j]; pe += s_esum[base + j]; }
    s_pc[tid] = pc; s_pe[tid] = pe;
    __syncthreads();
    for (int off = 1; off < T; off <<= 1) {
      unsigned cp = 0; float ep = 0.f;
      if (tid >= off) { cp = s_pc[tid - off]; ep = s_pe[tid - off]; }
      __syncthreads();
      s_pc[tid] += cp; s_pe[tid] += ep;
      __syncthreads();
    }
    const int accA0 = s_accA; const float accE0 = s_accE;
    int ca = accA0 + (int)(tid ? s_pc[tid - 1] : 0u);
    float ea = accE0 + (tid ? s_pe[tid - 1] : 0.f);
    int found = NB2;
#pragma unroll
    for (int j = 0; j < NB2 / T; j++) {
      int cb = (int)s_cnt[base + j]; float eb = s_esum[base + j];
      if ((ca + cb > K) || (ea + eb > thresh)) { found = base + j; break; }
      ca += cb; ea += eb;
    }
    if (found < NB2) atomicMin(&s_fstar, found);
    __syncthreads();
    if (s_fstar == NB2 && tid == 0) s_fstar = NB2 - 1;   // fp-jitter fallback
    __syncthreads();
    const int fstar = s_fstar;
    if (tid == (fstar / (NB2 / T))) {
      int ca2 = accA0 + (int)(tid ? s_pc[tid - 1] : 0u);
      float ea2 = accE0 + (tid ? s_pe[tid - 1] : 0.f);
      for (int j = tid * (NB2 / T); j < fstar; j++) { ca2 += (int)s_cnt[j]; ea2 += s_esum[j]; }
      s_accA2 = ca2; s_accE2 = ea2;
    }
  }
  __syncthreads();
  const int fstar = s_fstar;

  // gather fine boundary-bin candidates from the list
  for (int i = tid; i < M1; i += T) {
    float t = s_xl[i];
    if (bin2_of(hi2, t) == fstar) {
      unsigned p = atomicAdd(&s_num2, 1u);
      if (p < (unsigned)XCAP2) { s_x2[p] = t; s_i2[p] = s_il[i]; }
    }
  }
  __syncthreads();

  // ---- exact walk in (value desc, index asc) order, exclusive tests ----
  if (tid == 0) {
    int M2 = (int)(s_num2 < (unsigned)XCAP2 ? s_num2 : (unsigned)XCAP2);
    int accA = s_accA2; float accE = s_accE2;
    float tstar = FLT_MAX; int istar = -1;
    for (;;) {
      float best = -FLT_MAX; int bidx = 0x7fffffff; bool found = false;
      for (int i = 0; i < M2; i++) {
        float xv = s_x2[i]; int iv = s_i2[i];
        bool after = (xv < tstar) || (xv == tstar && iv > istar);
        if (!after) continue;
        if (!found || xv > best || (xv == best && iv < bidx)) {
          best = xv; bidx = iv; found = true;
        }
      }
      if (!found) break;
      if (accA < K && accE <= thresh) {
        accA++; accE += __expf(best - m);
        tstar = best; istar = bidx;
      } else break;
    }
    RowStats st;
    st.m = m; st.tstar = tstar; st.Z = accE;
    st.bstar = bstar; st.fstar = fstar; st.istar = istar;
    st.pad[0] = st.pad[1] = 0;
    stats[n] = st;
  }
}

// ---------------- final: in-place masked softmax ----------------
__global__ __launch_bounds__(256)
void sampler_final(float* __restrict__ buf, const RowStats* __restrict__ stats)
{
  int n = blockIdx.y;
  int v = blockIdx.x * 256 + threadIdx.x;
  if (v >= V) return;
  RowStats st = stats[n];
  float x = buf[(size_t)n * V + v];
  int b = bin1_of(st.m, x);
  bool kept;
  if (b < st.bstar) kept = true;
  else if (b > st.bstar) kept = false;
  else {
    float hi2 = hi2_of(st.m, st.bstar);
    int b2 = bin2_of(hi2, x);
    kept = (b2 < st.fstar) ||
           (b2 == st.fstar && (x > st.tstar || (x == st.tstar && v <= st.istar)));
  }
  buf[(size_t)n * V + v] = kept ? (__expf(x - st.m) / st.Z) : 0.f;
}

extern "C" void kernel_launch(void* const* d_in, const int* in_sizes, int n_in,
                              void* d_out, int out_size, void* d_ws, size_t ws_size,
                              hipStream_t stream) {
  const float* hs    = (const float*)d_in[0];
  const float* emb   = (const float*)d_in[1];
  const int*   toks  = (const int*)d_in[2];
  const float* pres  = (const float*)d_in[3];
  const float* freq  = (const float*)d_in[4];
  const float* rep   = (const float*)d_in[5];
  const float* temps = (const float*)d_in[6];
  const float* tps   = (const float*)d_in[7];
  const int*   tks   = (const int*)d_in[8];
  float* out = (float*)d_out;

  char* ws = (char*)d_ws;
  RowStats* stats = (RowStats*)ws;                        // 4 KB
  ushort* Ahi = (ushort*)(ws + 8192);                     // 1 MB
  ushort* Alo = (ushort*)(ws + 8192 + (size_t)N * H * 2); // 1 MB

  sampler_prep  <<<dim3(N * H / 1024),        dim3(256), 0, stream>>>(hs, Ahi, Alo);
  sampler_gemm  <<<dim3((V + 63) / 64),       dim3(256), 0, stream>>>(Ahi, Alo, emb, temps, out);
  sampler_fixup <<<dim3(N),                   dim3(256), 0, stream>>>(out, toks, pres, freq, rep, temps);
  sampler_select<<<dim3(N),                   dim3(512), 0, stream>>>(out, tps, tks, stats);
  sampler_final <<<dim3((V + 255) / 256, N),  dim3(256), 0, stream>>>(out, stats);
}